// Round 12
// baseline (2360.877 us; speedup 1.0000x reference)
//
#include <hip/hip_runtime.h>
#include <hip/hip_bf16.h>
#include <hip/hip_fp16.h>
#include <cstdint>
#include <cstddef>

typedef unsigned short u16;
typedef unsigned long long u64;
typedef short s8v __attribute__((ext_vector_type(8)));
typedef float f4v __attribute__((ext_vector_type(4)));
typedef _Float16 f16x2 __attribute__((ext_vector_type(2)));

#define DI __device__ __forceinline__

#if defined(__has_builtin)
#  if __has_builtin(__builtin_amdgcn_fdot2)
#    define HAS_FDOT2 1
#  endif
#endif

// ---------- helpers ----------
DI u16 f2bf(float f){ unsigned u = __float_as_uint(f); u += 0x7fffu + ((u>>16)&1u); return (u16)(u>>16); }
DI float bf2f(u16 h){ return __uint_as_float(((unsigned)h)<<16); }
DI int ocol(int pc){ return ((pc>>3)&3)*512 + (pc>>5)*8 + (pc&7); }  // packed col -> original col
// slot layout (gate-contiguous): slot s = hb*32 + jj*4 + g  ->  original col
DI int ocol2(int s){ int pc = (s & ~31) | ((s&3)<<3) | ((s>>2)&7); return ocol(pc); }
DI int pc2slot(int pc){ return (pc & ~31) | ((pc&7)<<2) | ((pc>>3)&3); }
DI float sigm(float x){ x = fminf(fmaxf(x,-30.f),30.f); return 1.f/(1.f+__expf(-x)); }
DI float tanhx(float x){ x = fminf(fmaxf(x,-15.f),15.f); float e = __expf(-2.f*x); return (1.f-e)/(1.f+e); }
DI uint4 packh8(const u16* h){
  uint4 r; r.x=(unsigned)h[0]|((unsigned)h[1]<<16); r.y=(unsigned)h[2]|((unsigned)h[3]<<16);
  r.z=(unsigned)h[4]|((unsigned)h[5]<<16); r.w=(unsigned)h[6]|((unsigned)h[7]<<16); return r;
}
DI s8v u4s8(uint4 u){ union{uint4 a; s8v b;} t; t.a=u; return t.b; }

// f16-pair dot: acc += w.lo*hv.lo + w.hi*hv.hi
DI float qdot(unsigned w, f16x2 hv, float acc){
#ifdef HAS_FDOT2
  f16x2 wv; __builtin_memcpy(&wv, &w, 4);
  return __builtin_amdgcn_fdot2(wv, hv, acc, false);
#else
  __half2 hp = *reinterpret_cast<const __half2*>(&w);
  return acc + (float)hv[0]*__half2float(hp.x) + (float)hv[1]*__half2float(hp.y);
#endif
}

// ---------- agent-coherent (fence-free) access helpers ----------
DI unsigned cohld32(const void* p){
  return __hip_atomic_load((const unsigned*)p, __ATOMIC_RELAXED, __HIP_MEMORY_SCOPE_AGENT);
}
DI u64 cohld64(const void* p){
  return __hip_atomic_load((const u64*)p, __ATOMIC_RELAXED, __HIP_MEMORY_SCOPE_AGENT);
}
DI f4v cohldf4(const float* p){
  u64 lo = cohld64(p);
  u64 hi = cohld64(p + 2);
  f4v r;
  r[0]=__uint_as_float((unsigned)lo); r[1]=__uint_as_float((unsigned)(lo>>32));
  r[2]=__uint_as_float((unsigned)hi); r[3]=__uint_as_float((unsigned)(hi>>32));
  return r;
}
DI void cohst32(void* p, unsigned v){
  __hip_atomic_store((unsigned*)p, v, __ATOMIC_RELAXED, __HIP_MEMORY_SCOPE_AGENT);
}
DI void cohst64(void* p, u64 v){
  __hip_atomic_store((u64*)p, v, __ATOMIC_RELAXED, __HIP_MEMORY_SCOPE_AGENT);
}

// ---------- mega-builder: all independent precompute jobs in ONE launch ----------
__global__ __launch_bounds__(256) void k_build(
    const float* __restrict__ bb, const float* __restrict__ eh, const float* __restrict__ ec,
    const int* __restrict__ dec, const float* __restrict__ enc, const float* __restrict__ emb,
    const float* __restrict__ Wx, const float* __restrict__ Uh, const float* __restrict__ Wm,
    const float* __restrict__ Wq, const float* __restrict__ Wa, const float* __restrict__ Wf,
    float* __restrict__ bp, float* __restrict__ cst, unsigned* __restrict__ flags,
    u16* __restrict__ hhi, u16* __restrict__ hlo, u16* __restrict__ encB,
    u16* __restrict__ wq2, u16* __restrict__ wmT, u16* __restrict__ waT,
    u16* __restrict__ wxtpT, u16* __restrict__ wxaT, u16* __restrict__ buhT,
    u16* __restrict__ waA, u16* __restrict__ embB, u16* __restrict__ WfT){
  __shared__ u16 T[64*72];
  int lb = blockIdx.x, tid = threadIdx.x;
  if (lb < 638){                                   // J0: scalar init (bp, cst, flags)
    int i = lb*256 + tid;
    if (i < 2048) bp[i] = bb[ocol2(i)];
    else if (i < 2048+32768) cst[i-2048] = ec[i-2048];
    else if (i < 2048+32768+30208) flags[i-34816] = 0u;
  } else if (lb < 1022){                           // J1: hcat init (hi/lo) into buffer slot 3
    int i = (lb-638)*256 + tid; if (i >= 64*1536) return;
    int c = i % 1536;
    float f = (c < 512) ? eh[(i/1536)*512 + c] : 0.f;
    u16 hi = f2bf(f);
    hhi[i] = hi;
    hlo[i] = (c < 512) ? f2bf(f - bf2f(hi)) : (u16)0;
  } else if (lb < 2046){                           // J2: enc -> bf16
    int g = (lb-1022)*256 + tid; if (g >= 262144) return;
    const float4* p = (const float4*)(enc + (size_t)g*8);
    float4 a = p[0], b = p[1];
    u16 h[8] = {f2bf(a.x),f2bf(a.y),f2bf(a.z),f2bf(a.w),f2bf(b.x),f2bf(b.y),f2bf(b.z),f2bf(b.w)};
    *(uint4*)&encB[(size_t)g*8] = packh8(h);
  } else if (lb < 3070){                           // J3: Wq -> f16 pair-interleaved
    int g = (lb-2046)*256 + tid; if (g >= 262144) return;
    int h = g>>9, c = g&511;
    __half hf = __float2half(Wq[g]);
    wq2[(size_t)(h>>1)*1024 + (c<<1) + (h&1)] = *reinterpret_cast<u16*>(&hf);
  } else if (lb < 3326){                           // J4: Wm^T
    int g = (lb-3070)*256 + tid; if (g >= 512*128) return;
    int hcol = g/128, o = g%128;
    u16 h[8];
    #pragma unroll
    for(int j=0;j<8;++j){ int m = o*8+j; h[j]=f2bf(Wm[(size_t)m*512 + hcol]); }
    *(uint4*)&wmT[(size_t)hcol*1024 + o*8] = packh8(h);
  } else if (lb < 3710){                           // J5: Wa^T
    int g = (lb-3326)*256 + tid; if (g >= 512*192) return;
    int c = g/192, o = g%192;
    u16 h[8];
    #pragma unroll
    for(int j=0;j<8;++j){ int k = o*8+j; h[j]=f2bf(Wa[(size_t)k*512 + c]); }
    *(uint4*)&waT[(size_t)c*1536 + o*8] = packh8(h);
  } else if (lb < 4030){                           // J6: Wx top (slot cols)
    int g = (lb-3710)*256 + tid; if (g >= 2048*40) return;
    int pc = g/40, o = g%40; int oc = ocol2(pc);
    u16 h[8];
    #pragma unroll
    for(int j=0;j<8;++j){ int e = o*8+j; float f = (e<300)? Wx[(size_t)e*2048 + oc] : 0.f; h[j]=f2bf(f); }
    *(uint4*)&wxtpT[(size_t)pc*320 + o*8] = packh8(h);
  } else if (lb < 5566){                           // J7: Wx_att^T splits
    int g = (lb-4030)*256 + tid; if (g >= 2048*192) return;
    int pc = g/192, o = g%192; int oc = ocol(pc);
    u16 h[8];
    #pragma unroll
    for(int j=0;j<8;++j){
      int kp = o*8+j; int seg = kp>>9; int jd = kp&511;
      float f = Wx[(size_t)(300+jd)*2048 + oc];
      u16 hi = f2bf(f);
      h[j] = (seg==2) ? f2bf(f - bf2f(hi)) : hi;
    }
    *(uint4*)&wxaT[(size_t)pc*1536 + o*8] = packh8(h);
  } else if (lb < 6590){                           // J8: Uh^T splits
    int g = (lb-5566)*256 + tid; if (g >= 2048*128) return;
    int pc = g/128, o = g%128; int oc = ocol(pc);
    u16 h[8];
    #pragma unroll
    for(int j=0;j<8;++j){
      int kp = o*8+j; int r = kp&511;
      float f = Uh[(size_t)r*2048 + oc];
      u16 hi = f2bf(f);
      h[j] = (kp<512) ? hi : f2bf(f - bf2f(hi));
    }
    *(uint4*)&buhT[(size_t)pc*1024 + o*8] = packh8(h);
  } else if (lb < 7742){                           // J9: Wa splits (A side)
    int g = (lb-6590)*256 + tid; if (g >= 1536*192) return;
    int r = g/192, o = g%192;
    u16 h[8];
    #pragma unroll
    for(int j=0;j<8;++j){
      int kp = o*8+j; int seg = kp>>9; int jd = kp&511;
      float f = Wa[(size_t)r*512 + jd];
      u16 hi = f2bf(f);
      h[j] = (seg==1) ? f2bf(f - bf2f(hi)) : hi;
    }
    *(uint4*)&waA[(size_t)r*1536 + o*8] = packh8(h);
  } else if (lb < 8332){                           // J10: embedding gather
    int g = (lb-7742)*256 + tid; if (g >= 3776*40) return;
    int row = g/40, o = g%40;
    int b = row & 63, t = row >> 6;
    int tok = dec[b*59 + t];
    u16 h[8];
    #pragma unroll
    for(int j=0;j<8;++j){ int k = o*8+j; float f = (k<300)? emb[(size_t)tok*300 + k] : 0.f; h[j]=f2bf(f); }
    *(uint4*)&embB[(size_t)row*320 + o*8] = packh8(h);
  } else {                                         // J11: Wf transpose
    int lb2 = lb - 8332;
    int n0 = (lb2 % 532)*64, k0 = (lb2/532)*64;
    int kl = tid>>2, nq = (tid&3)*16;
    u16 h[16];
    if (n0 + 64 <= 34004){
      const float4* p = (const float4*)(Wf + (size_t)(k0+kl)*34004 + n0 + nq);
      #pragma unroll
      for(int q=0;q<4;++q){ float4 f = p[q]; h[q*4+0]=f2bf(f.x); h[q*4+1]=f2bf(f.y); h[q*4+2]=f2bf(f.z); h[q*4+3]=f2bf(f.w); }
    } else {
      #pragma unroll
      for(int j=0;j<16;++j){ int n = n0+nq+j; float f = (n<34004)? Wf[(size_t)(k0+kl)*34004 + n] : 0.f; h[j]=f2bf(f); }
    }
    *(uint4*)&T[kl*72 + nq] = packh8(h);
    *(uint4*)&T[kl*72 + nq + 8] = packh8(h+8);
    __syncthreads();
    int nl = tid>>2, kq = (tid&3)*16;
    int n = n0 + nl;
    if (n < 34004){
      u16 o[16];
      #pragma unroll
      for(int j=0;j<16;++j) o[j] = T[(kq+j)*72 + nl];
      *(uint4*)&WfT[(size_t)n*512 + k0 + kq]     = packh8(o);
      *(uint4*)&WfT[(size_t)n*512 + k0 + kq + 8] = packh8(o+8);
    }
  }
}

// (WzcT + Uh-on-top)^T splits: phys [hi(1536) | lo(1536)]
__global__ void k_wzcT(const float* __restrict__ wzcT, const float* __restrict__ Uh, u16* __restrict__ dst){
  int g = blockIdx.x*256 + threadIdx.x; if (g >= 2048*384) return;
  int pc = g/384, o = g%384; int oc = ocol(pc);
  u16 h[8];
  #pragma unroll
  for(int j=0;j<8;++j){
    int kp = o*8+j; int r = kp % 1536;
    float f = wzcT[(size_t)pc*1536 + r] + ((r<512) ? Uh[(size_t)r*2048 + oc] : 0.f);
    u16 hi = f2bf(f);
    h[j] = (kp<1536) ? hi : f2bf(f - bf2f(hi));
  }
  *(uint4*)&dst[(size_t)pc*3072 + o*8] = packh8(h);
}

// ---------- 128x128 bf16 MFMA GEMM core (device fn, 256 threads) ----------
template<int EPI>
DI void gemm_dev(int bx, int by, u16* LSbuf,
    const u16* __restrict__ A, const u16* __restrict__ Bt,
    int M, int N, int K,
    float* __restrict__ Cf, u16* __restrict__ Cb,
    const float* __restrict__ bias, float* __restrict__ Cout){
  u16* Als = LSbuf;
  u16* Bls = LSbuf + 128*40;
  int tid = threadIdx.x;
  int c0 = bx*128, r0 = by*128;
  int wid = tid>>6, wr = wid>>1, wc = wid&1;
  int l15 = tid&15, l4 = (tid>>4)&3;
  f4v acc[4][4];
  #pragma unroll
  for(int m=0;m<4;++m)
  #pragma unroll
  for(int n=0;n<4;++n)
  #pragma unroll
  for(int i=0;i<4;++i) acc[m][n][i] = 0.f;

  int r = tid>>1, hf = tid&1;
  size_t arow = (size_t)min(r0 + r, M-1);
  size_t brow = (size_t)min(c0 + r, N-1);
  const u16* abase = A  + arow*K + hf*16;
  const u16* bbase = Bt + brow*K + hf*16;
  int nk = K >> 5;
  uint4 a0 = ((const uint4*)abase)[0], a1 = ((const uint4*)abase)[1];
  uint4 b0 = ((const uint4*)bbase)[0], b1 = ((const uint4*)bbase)[1];
  for (int ch=0; ch<nk; ++ch){
    __syncthreads();
    *(uint4*)&Als[r*40 + hf*16]     = a0;
    *(uint4*)&Als[r*40 + hf*16 + 8] = a1;
    *(uint4*)&Bls[r*40 + hf*16]     = b0;
    *(uint4*)&Bls[r*40 + hf*16 + 8] = b1;
    __syncthreads();
    if (ch+1 < nk){
      const uint4* ap = (const uint4*)(abase + (ch+1)*32);
      const uint4* bp = (const uint4*)(bbase + (ch+1)*32);
      a0 = ap[0]; a1 = ap[1]; b0 = bp[0]; b1 = bp[1];
    }
    s8v af[4], bfr[4];
    #pragma unroll
    for(int m=0;m<4;++m) af[m]  = *(const s8v*)&Als[(wr*64 + m*16 + l15)*40 + l4*8];
    #pragma unroll
    for(int n=0;n<4;++n) bfr[n] = *(const s8v*)&Bls[(wc*64 + n*16 + l15)*40 + l4*8];
    #pragma unroll
    for(int m=0;m<4;++m)
    #pragma unroll
    for(int n=0;n<4;++n)
      acc[m][n] = __builtin_amdgcn_mfma_f32_16x16x32_bf16(af[m], bfr[n], acc[m][n], 0,0,0);
  }
  __syncthreads();
  float* eps = ((float*)LSbuf) + wid*1024;   // 16 rows x 64 cols per wave
  #pragma unroll
  for(int m=0;m<4;++m){
    #pragma unroll
    for(int n=0;n<4;++n)
    #pragma unroll
    for(int i=0;i<4;++i)
      eps[(l4*4 + i)*64 + n*16 + l15] = acc[m][n][i];
    #pragma unroll
    for(int q=0;q<4;++q){
      int row = l4 + q*4;
      f4v v = *(const f4v*)&eps[row*64 + l15*4];
      int gr = r0 + wr*64 + m*16 + row;
      int gc = c0 + wc*64 + l15*4;
      if (gr < M && gc < N){
        if constexpr (EPI==0){
          *(f4v*)&Cf[(size_t)gr*N + gc] = v;
        } else if constexpr (EPI==1){
          f4v bv = *(const f4v*)&bias[gc];
          v += bv;
          *(f4v*)&Cf[(size_t)gr*N + gc] = v;
        } else if constexpr (EPI==2){
          unsigned p0 = ((unsigned)f2bf(v[1])<<16) | f2bf(v[0]);
          unsigned p1 = ((unsigned)f2bf(v[3])<<16) | f2bf(v[2]);
          uint2 pk; pk.x = p0; pk.y = p1;
          *(uint2*)&Cb[(size_t)gr*N + gc] = pk;
        } else {
          f4v bv = *(const f4v*)&bias[gc];
          v += bv;
          int b_ = gr&63, tt = gr>>6;
          *(f4v*)&Cout[((size_t)(b_*59 + tt))*34004 + gc] = v;
        }
      }
    }
  }
}

template<int EPI>
__global__ __launch_bounds__(256,2) void gemm_bf16(
    const u16* __restrict__ A, const u16* __restrict__ Bt,
    int M, int N, int K,
    float* __restrict__ Cf, u16* __restrict__ Cb,
    const float* __restrict__ bias, float* __restrict__ Cout){
  __shared__ u16 LSbuf[2*128*40];
  gemm_dev<EPI>(blockIdx.x, blockIdx.y, LSbuf, A, Bt, M, N, K, Cf, Cb, bias, Cout);
}

// merged precompute GEMMs: Zemb(480) + keys(64) + WzcT(192) in one launch
__global__ __launch_bounds__(256,2) void k_gemm3(
    const u16* __restrict__ embB, const u16* __restrict__ wxtpT, float* __restrict__ Zemb,
    const float* __restrict__ bp,
    const u16* __restrict__ encB, const u16* __restrict__ wmT, float* __restrict__ keys,
    const u16* __restrict__ wxaT, const u16* __restrict__ waA, float* __restrict__ wzc){
  __shared__ u16 LSbuf[2*128*40];
  int b = blockIdx.x;
  if (b < 480){
    gemm_dev<1>(b%16, b/16, LSbuf, embB, wxtpT, 3776, 2048, 320, Zemb, nullptr, bp, nullptr);
  } else if (b < 544){
    int b2 = b-480;
    gemm_dev<0>(b2%4, b2/4, LSbuf, encB, wmT, 2048, 512, 1024, keys, nullptr, nullptr, nullptr);
  } else {
    int b3 = b-544;
    gemm_dev<0>(b3%12, b3/12, LSbuf, wxaT, waA, 2048, 1536, 1536, wzc, nullptr, nullptr, nullptr);
  }
}

// ---------- multi-step fused kernel: ns steps per launch ----------
// grid 320 x 512 thr (co-resident: 64KB LDS, <=128 VGPR -> 2 blocks/CU x 256 = 512).
// Rotating hcat buffers hh/hl[4][64*1536]: attention at step t writes buffer (t&3)
// via agent-scope stores (drained before flagging); z-blocks at step t normal-read
// buffer ((t-1)&3) -- each buffer is FIRST-TOUCHED once per launch after the
// launch-start L2 invalidate, so normal reads fetch fresh data from the coherence
// point. Per intra-launch step: attn blocks flag after drain; b0 aggregates and
// publishes attn-done word; z-blocks poll that single word.
__global__ __launch_bounds__(512,4) void stepN(
    int t0, int ns,
    const u16* __restrict__ wzT, const u16* __restrict__ buhT,
    u16* __restrict__ hh, u16* __restrict__ hl,
    float* __restrict__ zparts, const float* __restrict__ Zemb,
    float* __restrict__ cst,
    const u16* __restrict__ wq2, const float* __restrict__ keys,
    const u16* __restrict__ encB, const float* __restrict__ vv,
    unsigned* __restrict__ flags, u16* __restrict__ A2c){
  __shared__ float smem[16384];   // 64 KB
  int bid = blockIdx.x, tid = threadIdx.x;

  if (bid < 256){
    // ---------------- z role ----------------
    int sl = bid>>6, cg = bid&63;
    int pc0 = cg*32;
    int wv = tid>>6, lane = tid&63;
    int l15 = lane&15, l4 = lane>>4;
    for (int k=0; k<ns; ++k){
      int t = t0 + k;
      unsigned* flg = flags + (size_t)t*512;
      if (k > 0){
        unsigned* pf = flags + (size_t)(t-1)*512 + 320;
        if (tid==0){ while (cohld32(pf) == 0u) __builtin_amdgcn_s_sleep(1); }
        __syncthreads();
        asm volatile("" ::: "memory");
      }
      int variant = (t==0) ? 0 : 1;
      const u16* hhi = hh + (size_t)((t+3)&3)*98304;
      const u16* hlo = hl + (size_t)((t+3)&3)*98304;
      const u16* Bt = variant ? wzT : buhT;
      int physK = variant ? 3072 : 1024;
      int CS = variant ? 36 : 12;
      int ck0 = sl*CS, ck1 = ck0 + CS;

      f4v acc[4][2];
      #pragma unroll
      for(int m=0;m<4;++m)
      #pragma unroll
      for(int n=0;n<2;++n)
      #pragma unroll
      for(int i=0;i<4;++i) acc[m][n][i] = 0.f;

      for (int c = ck0 + wv; c < ck1; c += 8){
        int k1 = c*32;
        const u16* ap; int inner, kB;
        if (variant==0){
          inner = k1 & 511;
          ap = ((((k1>>9)&3)==1) ? hlo : hhi);
          kB = (k1 < 1024) ? (k1 & 511) : (k1 - 512);
        } else {
          int sg = k1/1536; inner = k1 - sg*1536;
          ap = (sg==1) ? hlo : hhi;
          kB = (k1 < 3072) ? (k1 % 1536) : (1536 + (k1 - 3072));
        }
        uint4 av[4], bv[2];
        #pragma unroll
        for(int m=0;m<4;++m)
          av[m] = *(const uint4*)(ap + (size_t)(m*16 + l15)*1536 + inner + l4*8);
        #pragma unroll
        for(int n=0;n<2;++n)
          bv[n] = *(const uint4*)(Bt + (size_t)(pc0 + n*16 + l15)*physK + kB + l4*8);
        #pragma unroll
        for(int m=0;m<4;++m){
          s8v am = u4s8(av[m]);
          #pragma unroll
          for(int n=0;n<2;++n)
            acc[m][n] = __builtin_amdgcn_mfma_f32_16x16x32_bf16(am, u4s8(bv[n]), acc[m][n], 0,0,0);
        }
      }
      // LDS reduce across the 8 K-interleaved waves
      float* red = smem + wv*2048;
      #pragma unroll
      for(int m=0;m<4;++m)
      #pragma unroll
      for(int n=0;n<2;++n)
      #pragma unroll
      for(int i=0;i<4;++i)
        red[(m*16 + l4*4 + i)*32 + n*16 + l15] = acc[m][n][i];
      __syncthreads();

      int rr = tid>>3, cq = (tid&7)*4;
      f4v s = *(const f4v*)&smem[rr*32 + cq];
      #pragma unroll
      for(int w=1;w<8;++w)
        s += *(const f4v*)&smem[w*2048 + rr*32 + cq];
      float* zp = zparts + (size_t)sl*131072 + (size_t)rr*2048 + pc0 + cq;
      cohst64(&zp[0], (u64)__float_as_uint(s[0]) | ((u64)__float_as_uint(s[1])<<32));
      cohst64(&zp[2], (u64)__float_as_uint(s[2]) | ((u64)__float_as_uint(s[3])<<32));
      asm volatile("s_waitcnt vmcnt(0)" ::: "memory");
      __syncthreads();
      if (tid==0) cohst32(&flg[bid], 1u);
    }

  } else {
    // ---------------- attention role (one block per batch) ----------------
    int b = bid - 256;
    int j = tid;
    int base = (j>>3)*32 + (j&7)*4;
    float vvj = vv[j];
    float creg = cst[(size_t)b*512 + j];      // LSTM cell state lives in a register

    for (int k=0; k<ns; ++k){
      int t = t0 + k;
      unsigned* flg = flags + (size_t)t*512;
      u16* hhT = hh + (size_t)(t&3)*98304;
      u16* hlT = hl + (size_t)(t&3)*98304;
      // prefetch (independent of z)
      f4v ze = *(const f4v*)&Zemb[(size_t)t*131072 + (size_t)b*2048 + base];
      // wait zDone: b0 aggregates 256 flags, publishes one word; others poll it
      if (b == 0){
        if (tid < 256){
          while (cohld32(&flg[tid]) == 0u) __builtin_amdgcn_s_sleep(2);
        }
        __syncthreads();
        if (tid==0) cohst32(&flg[511], 1u);
      } else {
        if (tid==0){
          while (cohld32(&flg[511]) == 0u) __builtin_amdgcn_s_sleep(1);
        }
        __syncthreads();
      }
      asm volatile("" ::: "memory");

      float* zl  = smem;            // 2048
      float* h2s = smem + 2048;     // 512
      float* vs2 = smem + 2560;     // 512
      float* qs  = smem + 3072;     // 512
      float* qpl = smem + 3584;     // 4096
      float* scl = smem + 7680;     // 32
      float* alw = smem + 7712;     // 32
      // z-sum gather (coherent, 4-deep) + LDS slot-scatter
      {
        int p4 = tid*4;
        f4v z0; z0[0]=0.f; z0[1]=0.f; z0[2]=0.f; z0[3]=0.f;
        #pragma unroll
        for(int s2=0; s2<4; ++s2)
          z0 += cohldf4(&zparts[(size_t)s2*131072 + (size_t)b*2048 + p4]);
        #pragma unroll
        for(int e=0;e<4;++e)
          zl[pc2slot(p4+e)] = z0[e];
      }
      __syncthreads();
      // LSTM: one unit per thread; writes A2c row (normal), cell stays in creg
      {
        f4v s4 = ze + *(const f4v*)&zl[base];
        float c2 = sigm(s4[1])*creg + sigm(s4[0])*tanhx(s4[2]);
        float h2 = sigm(s4[3])*tanhx(c2);
        creg = c2;
        h2s[j] = h2; vs2[j] = vvj;
        A2c[((size_t)t*64 + b)*1536 + j] = f2bf(h2);
      }
      __syncthreads();
      // hcat h-part: pack pairs from h2s -> agent-scope stores (intra-launch visible)
      if (tid < 256){
        int j0 = tid*2;
        float h0 = h2s[j0], h1 = h2s[j0+1];
        u16 a0 = f2bf(h0), a1 = f2bf(h1);
        cohst32(&hhT[(size_t)b*1536 + j0], (unsigned)a0 | ((unsigned)a1<<16));
        u16 b0_ = f2bf(h0 - bf2f(a0)), b1_ = f2bf(h1 - bf2f(a1));
        cohst32(&hlT[(size_t)b*1536 + j0], (unsigned)b0_ | ((unsigned)b1_<<16));
      }
      // q = h2 @ Wq : f16 pair-interleaved wq2, v_dot2
      {
        int c8 = (tid&63)*8, hs = tid>>6;
        float qp[8] = {0,0,0,0,0,0,0,0};
        const u16* wp = wq2 + (size_t)(hs*32)*1024 + c8*2;
        #pragma unroll 4
        for(int i=0;i<32;++i){
          int hp = hs*32 + i;
          f16x2 hv; hv[0] = (_Float16)h2s[2*hp]; hv[1] = (_Float16)h2s[2*hp+1];
          uint4 w0 = *(const uint4*)wp;
          uint4 w1 = *(const uint4*)(wp + 8);
          wp += 1024;
          qp[0]=qdot(w0.x,hv,qp[0]); qp[1]=qdot(w0.y,hv,qp[1]);
          qp[2]=qdot(w0.z,hv,qp[2]); qp[3]=qdot(w0.w,hv,qp[3]);
          qp[4]=qdot(w1.x,hv,qp[4]); qp[5]=qdot(w1.y,hv,qp[5]);
          qp[6]=qdot(w1.z,hv,qp[6]); qp[7]=qdot(w1.w,hv,qp[7]);
        }
        *(float4*)&qpl[hs*512 + c8]     = make_float4(qp[0],qp[1],qp[2],qp[3]);
        *(float4*)&qpl[hs*512 + c8 + 4] = make_float4(qp[4],qp[5],qp[6],qp[7]);
      }
      __syncthreads();
      { float s = 0.f; for(int hs=0; hs<8; ++hs) s += qpl[hs*512 + tid]; qs[tid] = s; }
      __syncthreads();
      // scores: 16 threads per s (32 s), 32 h each, float4 keys
      {
        int s = tid>>4, hh2 = tid&15;
        const float4* kb4 = (const float4*)(keys + ((size_t)(b*32 + s))*512 + hh2*32);
        float part = 0.f;
        #pragma unroll
        for(int i8=0;i8<8;++i8){
          float4 kv = kb4[i8];
          int h = hh2*32 + i8*4;
          part += vs2[h+0]*tanhx(kv.x + qs[h+0]);
          part += vs2[h+1]*tanhx(kv.y + qs[h+1]);
          part += vs2[h+2]*tanhx(kv.z + qs[h+2]);
          part += vs2[h+3]*tanhx(kv.w + qs[h+3]);
        }
        #pragma unroll
        for(int m=1;m<16;m<<=1) part += __shfl_xor(part, m, 64);
        if (hh2==0) scl[s] = part;
      }
      __syncthreads();
      // softmax over 32
      if (tid < 32){
        float sc = scl[tid];
        float mx = sc;
        #pragma unroll
        for(int m=1;m<32;m<<=1) mx = fmaxf(mx, __shfl_xor(mx, m, 64));
        float e = __expf(sc - mx);
        float sm = e;
        #pragma unroll
        for(int m=1;m<32;m<<=1) sm += __shfl_xor(sm, m, 64);
        alw[tid] = e/sm;
      }
      __syncthreads();
      // ctx: 2 adjacent cols per thread, bf16 encB loads; hcat ctx-part + A2c
      {
        const u16* eb = encB + (size_t)b*32768;
        int cc = tid*2;
        float c0 = 0.f, c1 = 0.f;
        for(int s=0;s<32;++s){
          float al = alw[s];
          unsigned ev = *(const unsigned*)&eb[(size_t)s*1024 + cc];
          c0 += al*bf2f((u16)(ev&0xffffu));
          c1 += al*bf2f((u16)(ev>>16));
        }
        u16 x0 = f2bf(c0), x1 = f2bf(c1);
        unsigned px = (unsigned)x0 | ((unsigned)x1<<16);
        cohst32(&hhT[(size_t)b*1536 + 512 + cc], px);
        *(unsigned*)&A2c[((size_t)t*64 + b)*1536 + 512 + cc] = px;
        u16 y0 = f2bf(c0 - bf2f(x0)), y1 = f2bf(c1 - bf2f(x1));
        cohst32(&hlT[(size_t)b*1536 + 512 + cc], (unsigned)y0 | ((unsigned)y1<<16));
      }
      // drain hcat stores, signal attn flag; b0 aggregates -> attn-done word
      asm volatile("s_waitcnt vmcnt(0)" ::: "memory");
      __syncthreads();
      if (tid==0) cohst32(&flg[256+b], 1u);
      if (b == 0){
        if (tid < 64){
          while (cohld32(&flg[256+tid]) == 0u) __builtin_amdgcn_s_sleep(1);
        }
        __syncthreads();
        if (tid==0) cohst32(&flg[320], 1u);
      }
    }
    // persist cell state for the next launch (boundary-coherent)
    cst[(size_t)b*512 + j] = creg;
  }
}

// ---------- host ----------
extern "C" void kernel_launch(void* const* d_in, const int* in_sizes, int n_in,
                              void* d_out, int out_size, void* d_ws, size_t ws_size,
                              hipStream_t stream){
  const int*   dec = (const int*)d_in[0];
  const float* enc = (const float*)d_in[1];
  const float* eh  = (const float*)d_in[2];
  const float* ec  = (const float*)d_in[3];
  const float* emb = (const float*)d_in[4];
  const float* Wx  = (const float*)d_in[5];
  const float* Uh  = (const float*)d_in[6];
  const float* bb  = (const float*)d_in[7];
  const float* Wm  = (const float*)d_in[8];
  const float* Wq  = (const float*)d_in[9];
  const float* vv  = (const float*)d_in[10];
  const float* Wa  = (const float*)d_in[11];
  const float* Wf  = (const float*)d_in[12];
  const float* bf  = (const float*)d_in[13];
  float* out = (float*)d_out;

  // ---- workspace carving ----
  char* w = (char*)d_ws; size_t off = 0;
  auto alloc = [&](size_t bytes)->char*{ char* p = w + off; off = (off + bytes + 255) & ~(size_t)255; return p; };
  u16* WfT   = (u16*)alloc((size_t)34004*512*2);
  u16* attn2 = (u16*)alloc((size_t)3776*512*2);
  size_t liveEnd = off;
  const size_t needB = (size_t)131<<20;
  bool fits = (ws_size >= liveEnd + needB);
  char* wb = fits ? (w + liveEnd) : (char*)d_out;
  size_t offb = 0;
  auto allocB = [&](size_t bytes)->char*{ char* p = wb + offb; offb = (offb + bytes + 255) & ~(size_t)255; return p; };

  u16* wzT   = (u16*)allocB((size_t)2048*3072*2);
  u16* buhT  = (u16*)allocB((size_t)2048*1024*2);
  u16* wq2   = (u16*)allocB((size_t)512*512*2);
  u16* waT   = (u16*)allocB((size_t)512*1536*2);
  u16* wmT   = (u16*)allocB((size_t)512*1024*2);
  u16* wxtpT = (u16*)allocB((size_t)2048*320*2);
  u16* wxaT  = (u16*)allocB((size_t)2048*1536*2);
  u16* waA   = (u16*)allocB((size_t)1536*1536*2);
  float* wzc = (float*)allocB((size_t)2048*1536*4);
  u16* embB  = (u16*)allocB((size_t)3776*320*2);
  u16* encB  = (u16*)allocB((size_t)2048*1024*2);
  float* Zemb  = (float*)allocB((size_t)3776*2048*4);
  float* keys  = (float*)allocB((size_t)2048*512*4);
  float* zparts= (float*)allocB((size_t)9*64*2048*4);
  float* cst   = (float*)allocB((size_t)64*512*4);
  float* bp    = (float*)allocB((size_t)2048*4);
  u16* A2c   = (u16*)allocB((size_t)3776*1536*2);
  u16* hh    = (u16*)allocB((size_t)4*64*1536*2);
  u16* hl    = (u16*)allocB((size_t)4*64*1536*2);
  unsigned* flags = (unsigned*)allocB((size_t)59*512*4);

  // ---- precompute: ONE mega-builder launch ----
  k_build<<<12588,256,0,stream>>>(bb, eh, ec, dec, enc, emb, Wx, Uh, Wm, Wq, Wa, Wf,
                                  bp, cst, flags,
                                  hh + (size_t)3*98304, hl + (size_t)3*98304,
                                  encB, wq2, wmT, waT,
                                  wxtpT, wxaT, buhT, waA, embB, WfT);

  // merged GEMMs: Zemb + keys + WzcT
  k_gemm3<<<736,256,0,stream>>>(embB, wxtpT, Zemb, bp, encB, wmT, keys, wxaT, waA, wzc);
  // W'z^T = split( WzcT + Uh(top) )^T   [2048][3072]
  k_wzcT<<<(2048*384+255)/256,256,0,stream>>>(wzc, Uh, wzT);

  // ---- recurrence: 4 steps per launch ----
  for (int t0=0; t0<59; t0+=4){
    int ns = (59 - t0 < 4) ? (59 - t0) : 4;
    stepN<<<320,512,0,stream>>>(t0, ns, wzT, buhT, hh, hl, zparts, Zemb,
                                cst, wq2, keys, encB, vv, flags, A2c);
  }

  // ---- deferred attn2 + logits ----
  gemm_bf16<2><<<dim3(4,30),256,0,stream>>>(A2c, waT, 3776, 512, 1536, nullptr, attn2, nullptr, nullptr);
  gemm_bf16<3><<<dim3(266,30),256,0,stream>>>(attn2, WfT, 3776, 34004, 512, nullptr, nullptr, bf, out);
}

// Round 13
// 1704.863 us; speedup vs baseline: 1.3848x; 1.3848x over previous
//
#include <hip/hip_runtime.h>
#include <hip/hip_bf16.h>
#include <hip/hip_fp16.h>
#include <cstdint>
#include <cstddef>

typedef unsigned short u16;
typedef unsigned long long u64;
typedef short s8v __attribute__((ext_vector_type(8)));
typedef float f4v __attribute__((ext_vector_type(4)));
typedef _Float16 f16x2 __attribute__((ext_vector_type(2)));

#define DI __device__ __forceinline__

#if defined(__has_builtin)
#  if __has_builtin(__builtin_amdgcn_fdot2)
#    define HAS_FDOT2 1
#  endif
#endif

// ---------- helpers ----------
DI u16 f2bf(float f){ unsigned u = __float_as_uint(f); u += 0x7fffu + ((u>>16)&1u); return (u16)(u>>16); }
DI float bf2f(u16 h){ return __uint_as_float(((unsigned)h)<<16); }
DI int ocol(int pc){ return ((pc>>3)&3)*512 + (pc>>5)*8 + (pc&7); }  // packed col -> original col
// slot layout (gate-contiguous): slot s = hb*32 + jj*4 + g  ->  original col
DI int ocol2(int s){ int pc = (s & ~31) | ((s&3)<<3) | ((s>>2)&7); return ocol(pc); }
DI int pc2slot(int pc){ return (pc & ~31) | ((pc&7)<<2) | ((pc>>3)&3); }
DI float sigm(float x){ x = fminf(fmaxf(x,-30.f),30.f); return 1.f/(1.f+__expf(-x)); }
DI float tanhx(float x){ x = fminf(fmaxf(x,-15.f),15.f); float e = __expf(-2.f*x); return (1.f-e)/(1.f+e); }
DI uint4 packh8(const u16* h){
  uint4 r; r.x=(unsigned)h[0]|((unsigned)h[1]<<16); r.y=(unsigned)h[2]|((unsigned)h[3]<<16);
  r.z=(unsigned)h[4]|((unsigned)h[5]<<16); r.w=(unsigned)h[6]|((unsigned)h[7]<<16); return r;
}
DI s8v u4s8(uint4 u){ union{uint4 a; s8v b;} t; t.a=u; return t.b; }

// f16-pair dot: acc += w.lo*hv.lo + w.hi*hv.hi
DI float qdot(unsigned w, f16x2 hv, float acc){
#ifdef HAS_FDOT2
  f16x2 wv; __builtin_memcpy(&wv, &w, 4);
  return __builtin_amdgcn_fdot2(wv, hv, acc, false);
#else
  __half2 hp = *reinterpret_cast<const __half2*>(&w);
  return acc + (float)hv[0]*__half2float(hp.x) + (float)hv[1]*__half2float(hp.y);
#endif
}

// ---------- agent-coherent (fence-free) access helpers ----------
DI unsigned cohld32(const void* p){
  return __hip_atomic_load((const unsigned*)p, __ATOMIC_RELAXED, __HIP_MEMORY_SCOPE_AGENT);
}
DI u64 cohld64(const void* p){
  return __hip_atomic_load((const u64*)p, __ATOMIC_RELAXED, __HIP_MEMORY_SCOPE_AGENT);
}
DI f4v cohldf4(const float* p){
  u64 lo = cohld64(p);
  u64 hi = cohld64(p + 2);
  f4v r;
  r[0]=__uint_as_float((unsigned)lo); r[1]=__uint_as_float((unsigned)(lo>>32));
  r[2]=__uint_as_float((unsigned)hi); r[3]=__uint_as_float((unsigned)(hi>>32));
  return r;
}
DI void cohst32(void* p, unsigned v){
  __hip_atomic_store((unsigned*)p, v, __ATOMIC_RELAXED, __HIP_MEMORY_SCOPE_AGENT);
}
DI void cohst64(void* p, u64 v){
  __hip_atomic_store((u64*)p, v, __ATOMIC_RELAXED, __HIP_MEMORY_SCOPE_AGENT);
}

// ---------- mega-builder: all independent precompute jobs in ONE launch ----------
__global__ __launch_bounds__(256) void k_build(
    const float* __restrict__ bb, const float* __restrict__ eh, const float* __restrict__ ec,
    const int* __restrict__ dec, const float* __restrict__ enc, const float* __restrict__ emb,
    const float* __restrict__ Wx, const float* __restrict__ Uh, const float* __restrict__ Wm,
    const float* __restrict__ Wq, const float* __restrict__ Wa, const float* __restrict__ Wf,
    float* __restrict__ bp, float* __restrict__ cst, unsigned* __restrict__ flags,
    u16* __restrict__ hhi, u16* __restrict__ hlo, u16* __restrict__ encB,
    u16* __restrict__ wq2, u16* __restrict__ wmT, u16* __restrict__ waT,
    u16* __restrict__ wxtpT, u16* __restrict__ wxaT, u16* __restrict__ buhT,
    u16* __restrict__ waA, u16* __restrict__ embB, u16* __restrict__ WfT){
  __shared__ u16 T[64*72];
  int lb = blockIdx.x, tid = threadIdx.x;
  if (lb < 638){                                   // J0: scalar init (bp, cst, flags)
    int i = lb*256 + tid;
    if (i < 2048) bp[i] = bb[ocol2(i)];
    else if (i < 2048+32768) cst[i-2048] = ec[i-2048];
    else if (i < 2048+32768+30208) flags[i-34816] = 0u;
  } else if (lb < 1022){                           // J1: hcat init (hi/lo)
    int i = (lb-638)*256 + tid; if (i >= 64*1536) return;
    int c = i % 1536;
    float f = (c < 512) ? eh[(i/1536)*512 + c] : 0.f;
    u16 hi = f2bf(f);
    hhi[i] = hi;
    hlo[i] = (c < 512) ? f2bf(f - bf2f(hi)) : (u16)0;
  } else if (lb < 2046){                           // J2: enc -> bf16
    int g = (lb-1022)*256 + tid; if (g >= 262144) return;
    const float4* p = (const float4*)(enc + (size_t)g*8);
    float4 a = p[0], b = p[1];
    u16 h[8] = {f2bf(a.x),f2bf(a.y),f2bf(a.z),f2bf(a.w),f2bf(b.x),f2bf(b.y),f2bf(b.z),f2bf(b.w)};
    *(uint4*)&encB[(size_t)g*8] = packh8(h);
  } else if (lb < 3070){                           // J3: Wq -> f16 pair-interleaved
    int g = (lb-2046)*256 + tid; if (g >= 262144) return;
    int h = g>>9, c = g&511;
    __half hf = __float2half(Wq[g]);
    wq2[(size_t)(h>>1)*1024 + (c<<1) + (h&1)] = *reinterpret_cast<u16*>(&hf);
  } else if (lb < 3326){                           // J4: Wm^T
    int g = (lb-3070)*256 + tid; if (g >= 512*128) return;
    int hcol = g/128, o = g%128;
    u16 h[8];
    #pragma unroll
    for(int j=0;j<8;++j){ int m = o*8+j; h[j]=f2bf(Wm[(size_t)m*512 + hcol]); }
    *(uint4*)&wmT[(size_t)hcol*1024 + o*8] = packh8(h);
  } else if (lb < 3710){                           // J5: Wa^T
    int g = (lb-3326)*256 + tid; if (g >= 512*192) return;
    int c = g/192, o = g%192;
    u16 h[8];
    #pragma unroll
    for(int j=0;j<8;++j){ int k = o*8+j; h[j]=f2bf(Wa[(size_t)k*512 + c]); }
    *(uint4*)&waT[(size_t)c*1536 + o*8] = packh8(h);
  } else if (lb < 4030){                           // J6: Wx top (slot cols)
    int g = (lb-3710)*256 + tid; if (g >= 2048*40) return;
    int pc = g/40, o = g%40; int oc = ocol2(pc);
    u16 h[8];
    #pragma unroll
    for(int j=0;j<8;++j){ int e = o*8+j; float f = (e<300)? Wx[(size_t)e*2048 + oc] : 0.f; h[j]=f2bf(f); }
    *(uint4*)&wxtpT[(size_t)pc*320 + o*8] = packh8(h);
  } else if (lb < 5566){                           // J7: Wx_att^T splits
    int g = (lb-4030)*256 + tid; if (g >= 2048*192) return;
    int pc = g/192, o = g%192; int oc = ocol(pc);
    u16 h[8];
    #pragma unroll
    for(int j=0;j<8;++j){
      int kp = o*8+j; int seg = kp>>9; int jd = kp&511;
      float f = Wx[(size_t)(300+jd)*2048 + oc];
      u16 hi = f2bf(f);
      h[j] = (seg==2) ? f2bf(f - bf2f(hi)) : hi;
    }
    *(uint4*)&wxaT[(size_t)pc*1536 + o*8] = packh8(h);
  } else if (lb < 6590){                           // J8: Uh^T splits
    int g = (lb-5566)*256 + tid; if (g >= 2048*128) return;
    int pc = g/128, o = g%128; int oc = ocol(pc);
    u16 h[8];
    #pragma unroll
    for(int j=0;j<8;++j){
      int kp = o*8+j; int r = kp&511;
      float f = Uh[(size_t)r*2048 + oc];
      u16 hi = f2bf(f);
      h[j] = (kp<512) ? hi : f2bf(f - bf2f(hi));
    }
    *(uint4*)&buhT[(size_t)pc*1024 + o*8] = packh8(h);
  } else if (lb < 7742){                           // J9: Wa splits (A side)
    int g = (lb-6590)*256 + tid; if (g >= 1536*192) return;
    int r = g/192, o = g%192;
    u16 h[8];
    #pragma unroll
    for(int j=0;j<8;++j){
      int kp = o*8+j; int seg = kp>>9; int jd = kp&511;
      float f = Wa[(size_t)r*512 + jd];
      u16 hi = f2bf(f);
      h[j] = (seg==1) ? f2bf(f - bf2f(hi)) : hi;
    }
    *(uint4*)&waA[(size_t)r*1536 + o*8] = packh8(h);
  } else if (lb < 8332){                           // J10: embedding gather
    int g = (lb-7742)*256 + tid; if (g >= 3776*40) return;
    int row = g/40, o = g%40;
    int b = row & 63, t = row >> 6;
    int tok = dec[b*59 + t];
    u16 h[8];
    #pragma unroll
    for(int j=0;j<8;++j){ int k = o*8+j; float f = (k<300)? emb[(size_t)tok*300 + k] : 0.f; h[j]=f2bf(f); }
    *(uint4*)&embB[(size_t)row*320 + o*8] = packh8(h);
  } else {                                         // J11: Wf transpose
    int lb2 = lb - 8332;
    int n0 = (lb2 % 532)*64, k0 = (lb2/532)*64;
    int kl = tid>>2, nq = (tid&3)*16;
    u16 h[16];
    if (n0 + 64 <= 34004){
      const float4* p = (const float4*)(Wf + (size_t)(k0+kl)*34004 + n0 + nq);
      #pragma unroll
      for(int q=0;q<4;++q){ float4 f = p[q]; h[q*4+0]=f2bf(f.x); h[q*4+1]=f2bf(f.y); h[q*4+2]=f2bf(f.z); h[q*4+3]=f2bf(f.w); }
    } else {
      #pragma unroll
      for(int j=0;j<16;++j){ int n = n0+nq+j; float f = (n<34004)? Wf[(size_t)(k0+kl)*34004 + n] : 0.f; h[j]=f2bf(f); }
    }
    *(uint4*)&T[kl*72 + nq] = packh8(h);
    *(uint4*)&T[kl*72 + nq + 8] = packh8(h+8);
    __syncthreads();
    int nl = tid>>2, kq = (tid&3)*16;
    int n = n0 + nl;
    if (n < 34004){
      u16 o[16];
      #pragma unroll
      for(int j=0;j<16;++j) o[j] = T[(kq+j)*72 + nl];
      *(uint4*)&WfT[(size_t)n*512 + k0 + kq]     = packh8(o);
      *(uint4*)&WfT[(size_t)n*512 + k0 + kq + 8] = packh8(o+8);
    }
  }
}

// (WzcT + Uh-on-top)^T splits: phys [hi(1536) | lo(1536)]
__global__ void k_wzcT(const float* __restrict__ wzcT, const float* __restrict__ Uh, u16* __restrict__ dst){
  int g = blockIdx.x*256 + threadIdx.x; if (g >= 2048*384) return;
  int pc = g/384, o = g%384; int oc = ocol(pc);
  u16 h[8];
  #pragma unroll
  for(int j=0;j<8;++j){
    int kp = o*8+j; int r = kp % 1536;
    float f = wzcT[(size_t)pc*1536 + r] + ((r<512) ? Uh[(size_t)r*2048 + oc] : 0.f);
    u16 hi = f2bf(f);
    h[j] = (kp<1536) ? hi : f2bf(f - bf2f(hi));
  }
  *(uint4*)&dst[(size_t)pc*3072 + o*8] = packh8(h);
}

// ---------- 128x128 bf16 MFMA GEMM core (device fn, 256 threads) ----------
template<int EPI>
DI void gemm_dev(int bx, int by, u16* LSbuf,
    const u16* __restrict__ A, const u16* __restrict__ Bt,
    int M, int N, int K,
    float* __restrict__ Cf, u16* __restrict__ Cb,
    const float* __restrict__ bias, float* __restrict__ Cout){
  u16* Als = LSbuf;
  u16* Bls = LSbuf + 128*40;
  int tid = threadIdx.x;
  int c0 = bx*128, r0 = by*128;
  int wid = tid>>6, wr = wid>>1, wc = wid&1;
  int l15 = tid&15, l4 = (tid>>4)&3;
  f4v acc[4][4];
  #pragma unroll
  for(int m=0;m<4;++m)
  #pragma unroll
  for(int n=0;n<4;++n)
  #pragma unroll
  for(int i=0;i<4;++i) acc[m][n][i] = 0.f;

  int r = tid>>1, hf = tid&1;
  size_t arow = (size_t)min(r0 + r, M-1);
  size_t brow = (size_t)min(c0 + r, N-1);
  const u16* abase = A  + arow*K + hf*16;
  const u16* bbase = Bt + brow*K + hf*16;
  int nk = K >> 5;
  uint4 a0 = ((const uint4*)abase)[0], a1 = ((const uint4*)abase)[1];
  uint4 b0 = ((const uint4*)bbase)[0], b1 = ((const uint4*)bbase)[1];
  for (int ch=0; ch<nk; ++ch){
    __syncthreads();
    *(uint4*)&Als[r*40 + hf*16]     = a0;
    *(uint4*)&Als[r*40 + hf*16 + 8] = a1;
    *(uint4*)&Bls[r*40 + hf*16]     = b0;
    *(uint4*)&Bls[r*40 + hf*16 + 8] = b1;
    __syncthreads();
    if (ch+1 < nk){
      const uint4* ap = (const uint4*)(abase + (ch+1)*32);
      const uint4* bp = (const uint4*)(bbase + (ch+1)*32);
      a0 = ap[0]; a1 = ap[1]; b0 = bp[0]; b1 = bp[1];
    }
    s8v af[4], bfr[4];
    #pragma unroll
    for(int m=0;m<4;++m) af[m]  = *(const s8v*)&Als[(wr*64 + m*16 + l15)*40 + l4*8];
    #pragma unroll
    for(int n=0;n<4;++n) bfr[n] = *(const s8v*)&Bls[(wc*64 + n*16 + l15)*40 + l4*8];
    #pragma unroll
    for(int m=0;m<4;++m)
    #pragma unroll
    for(int n=0;n<4;++n)
      acc[m][n] = __builtin_amdgcn_mfma_f32_16x16x32_bf16(af[m], bfr[n], acc[m][n], 0,0,0);
  }
  __syncthreads();
  float* eps = ((float*)LSbuf) + wid*1024;   // 16 rows x 64 cols per wave
  #pragma unroll
  for(int m=0;m<4;++m){
    #pragma unroll
    for(int n=0;n<4;++n)
    #pragma unroll
    for(int i=0;i<4;++i)
      eps[(l4*4 + i)*64 + n*16 + l15] = acc[m][n][i];
    #pragma unroll
    for(int q=0;q<4;++q){
      int row = l4 + q*4;
      f4v v = *(const f4v*)&eps[row*64 + l15*4];
      int gr = r0 + wr*64 + m*16 + row;
      int gc = c0 + wc*64 + l15*4;
      if (gr < M && gc < N){
        if constexpr (EPI==0){
          *(f4v*)&Cf[(size_t)gr*N + gc] = v;
        } else if constexpr (EPI==1){
          f4v bv = *(const f4v*)&bias[gc];
          v += bv;
          *(f4v*)&Cf[(size_t)gr*N + gc] = v;
        } else if constexpr (EPI==2){
          unsigned p0 = ((unsigned)f2bf(v[1])<<16) | f2bf(v[0]);
          unsigned p1 = ((unsigned)f2bf(v[3])<<16) | f2bf(v[2]);
          uint2 pk; pk.x = p0; pk.y = p1;
          *(uint2*)&Cb[(size_t)gr*N + gc] = pk;
        } else {
          f4v bv = *(const f4v*)&bias[gc];
          v += bv;
          int b_ = gr&63, tt = gr>>6;
          *(f4v*)&Cout[((size_t)(b_*59 + tt))*34004 + gc] = v;
        }
      }
    }
  }
}

template<int EPI>
__global__ __launch_bounds__(256,2) void gemm_bf16(
    const u16* __restrict__ A, const u16* __restrict__ Bt,
    int M, int N, int K,
    float* __restrict__ Cf, u16* __restrict__ Cb,
    const float* __restrict__ bias, float* __restrict__ Cout){
  __shared__ u16 LSbuf[2*128*40];
  gemm_dev<EPI>(blockIdx.x, blockIdx.y, LSbuf, A, Bt, M, N, K, Cf, Cb, bias, Cout);
}

// merged precompute GEMMs: Zemb(480) + keys(64) + WzcT(192) in one launch
__global__ __launch_bounds__(256,2) void k_gemm3(
    const u16* __restrict__ embB, const u16* __restrict__ wxtpT, float* __restrict__ Zemb,
    const float* __restrict__ bp,
    const u16* __restrict__ encB, const u16* __restrict__ wmT, float* __restrict__ keys,
    const u16* __restrict__ wxaT, const u16* __restrict__ waA, float* __restrict__ wzc){
  __shared__ u16 LSbuf[2*128*40];
  int b = blockIdx.x;
  if (b < 480){
    gemm_dev<1>(b%16, b/16, LSbuf, embB, wxtpT, 3776, 2048, 320, Zemb, nullptr, bp, nullptr);
  } else if (b < 544){
    int b2 = b-480;
    gemm_dev<0>(b2%4, b2/4, LSbuf, encB, wmT, 2048, 512, 1024, keys, nullptr, nullptr, nullptr);
  } else {
    int b3 = b-544;
    gemm_dev<0>(b3%12, b3/12, LSbuf, wxaT, waA, 2048, 1536, 1536, wzc, nullptr, nullptr, nullptr);
  }
}

// ---------- fused per-step kernel: z-GEMM + aggregator-sync + LSTM/attention ----------
// (round-11 proven structure; h2X/ctxX dead stores removed)
__global__ __launch_bounds__(512,4) void step_fused(
    int t,
    const u16* __restrict__ wzT, const u16* __restrict__ buhT,
    u16* __restrict__ hhi, u16* __restrict__ hlo,
    float* __restrict__ zparts, const float* __restrict__ Zemb,
    float* __restrict__ cst,
    const u16* __restrict__ wq2, const float* __restrict__ keys,
    const u16* __restrict__ encB, const float* __restrict__ vv,
    unsigned* __restrict__ flags, u16* __restrict__ A2c){
  __shared__ float smem[16384];   // 64 KB
  int bid = blockIdx.x, tid = threadIdx.x;
  unsigned* flg = flags + (size_t)t*512;
  int variant = (t==0) ? 0 : 1;

  if (bid < 256){
    // ---- z-GEMM block ----
    int sl = bid>>6, cg = bid&63;
    int pc0 = cg*32;
    int wv = tid>>6, lane = tid&63;
    int l15 = lane&15, l4 = lane>>4;
    const u16* Bt = variant ? wzT : buhT;
    int physK = variant ? 3072 : 1024;
    int CS = variant ? 36 : 12;        // K-chunks per slice (virtualK/32/4)
    int ck0 = sl*CS, ck1 = ck0 + CS;

    f4v acc[4][2];
    #pragma unroll
    for(int m=0;m<4;++m)
    #pragma unroll
    for(int n=0;n<2;++n)
    #pragma unroll
    for(int i=0;i<4;++i) acc[m][n][i] = 0.f;

    for (int c = ck0 + wv; c < ck1; c += 8){
      int k1 = c*32;
      const u16* ap; int inner, kB;
      if (variant==0){
        inner = k1 & 511;
        ap = ((((k1>>9)&3)==1) ? hlo : hhi);
        kB = (k1 < 1024) ? (k1 & 511) : (k1 - 512);
      } else {
        int sg = k1/1536; inner = k1 - sg*1536;
        ap = (sg==1) ? hlo : hhi;
        kB = (k1 < 3072) ? (k1 % 1536) : (1536 + (k1 - 3072));
      }
      uint4 av[4], bv[2];
      #pragma unroll
      for(int m=0;m<4;++m)
        av[m] = *(const uint4*)(ap + (size_t)(m*16 + l15)*1536 + inner + l4*8);
      #pragma unroll
      for(int n=0;n<2;++n)
        bv[n] = *(const uint4*)(Bt + (size_t)(pc0 + n*16 + l15)*physK + kB + l4*8);
      #pragma unroll
      for(int m=0;m<4;++m){
        s8v am = u4s8(av[m]);
        #pragma unroll
        for(int n=0;n<2;++n)
          acc[m][n] = __builtin_amdgcn_mfma_f32_16x16x32_bf16(am, u4s8(bv[n]), acc[m][n], 0,0,0);
      }
    }
    // LDS reduce across the 8 K-interleaved waves
    float* red = smem + wv*2048;
    #pragma unroll
    for(int m=0;m<4;++m)
    #pragma unroll
    for(int n=0;n<2;++n)
    #pragma unroll
    for(int i=0;i<4;++i)
      red[(m*16 + l4*4 + i)*32 + n*16 + l15] = acc[m][n][i];
    __syncthreads();

    int rr = tid>>3, cq = (tid&7)*4;
    f4v s = *(const f4v*)&smem[rr*32 + cq];
    #pragma unroll
    for(int w=1;w<8;++w)
      s += *(const f4v*)&smem[w*2048 + rr*32 + cq];
    float* zp = zparts + (size_t)sl*131072 + (size_t)rr*2048 + pc0 + cq;
    cohst64(&zp[0], (u64)__float_as_uint(s[0]) | ((u64)__float_as_uint(s[1])<<32));
    cohst64(&zp[2], (u64)__float_as_uint(s[2]) | ((u64)__float_as_uint(s[3])<<32));
    asm volatile("s_waitcnt vmcnt(0)" ::: "memory");
    __syncthreads();
    if (tid==0) cohst32(&flg[bid], 1u);

  } else {
    // ---- attention block (one per batch) ----
    int b = bid - 256;
    // prefetch step-t inputs that do NOT depend on z (hides latency under wait)
    int j = tid;
    int base = (j>>3)*32 + (j&7)*4;            // gate-slot base for unit j
    f4v ze = *(const f4v*)&Zemb[(size_t)t*131072 + (size_t)b*2048 + base];
    float cprev = cst[(size_t)b*512 + j];
    float vvj = vv[j];
    // sync: b0 aggregates 256 flags, publishes one done word; others poll it
    if (b == 0){
      if (tid < 256){
        while (cohld32(&flg[tid]) == 0u) __builtin_amdgcn_s_sleep(2);
      }
      __syncthreads();
      if (tid==0) cohst32(&flg[511], 1u);
    } else {
      if (tid==0){
        while (cohld32(&flg[511]) == 0u) __builtin_amdgcn_s_sleep(1);
      }
      __syncthreads();
    }
    asm volatile("" ::: "memory");

    float* zl  = smem;            // 2048
    float* h2s = smem + 2048;     // 512
    float* vs2 = smem + 2560;     // 512
    float* qs  = smem + 3072;     // 512
    float* qpl = smem + 3584;     // 4096
    float* scl = smem + 7680;     // 32
    float* alw = smem + 7712;     // 32
    // z-sum gather (coherent, 4-deep) + LDS slot-scatter
    {
      int p4 = tid*4;
      f4v z0; z0[0]=0.f; z0[1]=0.f; z0[2]=0.f; z0[3]=0.f;
      #pragma unroll
      for(int s2=0; s2<4; ++s2)
        z0 += cohldf4(&zparts[(size_t)s2*131072 + (size_t)b*2048 + p4]);
      #pragma unroll
      for(int e=0;e<4;++e)
        zl[pc2slot(p4+e)] = z0[e];
    }
    __syncthreads();
    // LSTM: one unit per thread; writes A2c row (t*64+b) cols 0..511
    {
      f4v s4 = ze + *(const f4v*)&zl[base];
      float c2 = sigm(s4[1])*cprev + sigm(s4[0])*tanhx(s4[2]);
      float h2 = sigm(s4[3])*tanhx(c2);
      cst[(size_t)b*512 + j] = c2;
      h2s[j] = h2; vs2[j] = vvj;
      u16 hh2 = f2bf(h2);
      hhi[(size_t)b*1536 + j] = hh2;
      hlo[(size_t)b*1536 + j] = f2bf(h2 - bf2f(hh2));
      A2c[((size_t)t*64 + b)*1536 + j] = hh2;
    }
    __syncthreads();
    // q = h2 @ Wq : f16 pair-interleaved wq2, v_dot2 (8 h-slices x 64 thr x 8 cols)
    {
      int c8 = (tid&63)*8, hs = tid>>6;
      float qp[8] = {0,0,0,0,0,0,0,0};
      const u16* wp = wq2 + (size_t)(hs*32)*1024 + c8*2;
      #pragma unroll 4
      for(int i=0;i<32;++i){
        int hp = hs*32 + i;
        f16x2 hv; hv[0] = (_Float16)h2s[2*hp]; hv[1] = (_Float16)h2s[2*hp+1];
        uint4 w0 = *(const uint4*)wp;
        uint4 w1 = *(const uint4*)(wp + 8);
        wp += 1024;
        qp[0]=qdot(w0.x,hv,qp[0]); qp[1]=qdot(w0.y,hv,qp[1]);
        qp[2]=qdot(w0.z,hv,qp[2]); qp[3]=qdot(w0.w,hv,qp[3]);
        qp[4]=qdot(w1.x,hv,qp[4]); qp[5]=qdot(w1.y,hv,qp[5]);
        qp[6]=qdot(w1.z,hv,qp[6]); qp[7]=qdot(w1.w,hv,qp[7]);
      }
      *(float4*)&qpl[hs*512 + c8]     = make_float4(qp[0],qp[1],qp[2],qp[3]);
      *(float4*)&qpl[hs*512 + c8 + 4] = make_float4(qp[4],qp[5],qp[6],qp[7]);
    }
    __syncthreads();
    { float s = 0.f; for(int hs=0; hs<8; ++hs) s += qpl[hs*512 + tid]; qs[tid] = s; }
    __syncthreads();
    // scores: 16 threads per s (32 s), 32 h each, float4 keys
    {
      int s = tid>>4, hh = tid&15;
      const float4* kb4 = (const float4*)(keys + ((size_t)(b*32 + s))*512 + hh*32);
      float part = 0.f;
      #pragma unroll
      for(int i8=0;i8<8;++i8){
        float4 kv = kb4[i8];
        int h = hh*32 + i8*4;
        part += vs2[h+0]*tanhx(kv.x + qs[h+0]);
        part += vs2[h+1]*tanhx(kv.y + qs[h+1]);
        part += vs2[h+2]*tanhx(kv.z + qs[h+2]);
        part += vs2[h+3]*tanhx(kv.w + qs[h+3]);
      }
      #pragma unroll
      for(int m=1;m<16;m<<=1) part += __shfl_xor(part, m, 64);
      if (hh==0) scl[s] = part;
    }
    __syncthreads();
    // softmax over 32
    if (tid < 32){
      float sc = scl[tid];
      float mx = sc;
      #pragma unroll
      for(int m=1;m<32;m<<=1) mx = fmaxf(mx, __shfl_xor(mx, m, 64));
      float e = __expf(sc - mx);
      float sm = e;
      #pragma unroll
      for(int m=1;m<32;m<<=1) sm += __shfl_xor(sm, m, 64);
      alw[tid] = e/sm;
    }
    __syncthreads();
    // ctx: 2 adjacent cols per thread, bf16 encB loads; writes A2c cols 512+
    {
      const u16* eb = encB + (size_t)b*32768;
      int cc = tid*2;
      float c0 = 0.f, c1 = 0.f;
      for(int s=0;s<32;++s){
        float al = alw[s];
        unsigned ev = *(const unsigned*)&eb[(size_t)s*1024 + cc];
        c0 += al*bf2f((u16)(ev&0xffffu));
        c1 += al*bf2f((u16)(ev>>16));
      }
      u16 x0 = f2bf(c0), x1 = f2bf(c1);
      unsigned px = (unsigned)x0 | ((unsigned)x1<<16);
      *(unsigned*)&hhi[(size_t)b*1536 + 512 + cc] = px;
      *(unsigned*)&A2c[((size_t)t*64 + b)*1536 + 512 + cc] = px;
      u16 y0 = f2bf(c0 - bf2f(x0)), y1 = f2bf(c1 - bf2f(x1));
      *(unsigned*)&hlo[(size_t)b*1536 + 512 + cc] = (unsigned)y0 | ((unsigned)y1<<16);
    }
  }
}

// ---------- host ----------
extern "C" void kernel_launch(void* const* d_in, const int* in_sizes, int n_in,
                              void* d_out, int out_size, void* d_ws, size_t ws_size,
                              hipStream_t stream){
  const int*   dec = (const int*)d_in[0];
  const float* enc = (const float*)d_in[1];
  const float* eh  = (const float*)d_in[2];
  const float* ec  = (const float*)d_in[3];
  const float* emb = (const float*)d_in[4];
  const float* Wx  = (const float*)d_in[5];
  const float* Uh  = (const float*)d_in[6];
  const float* bb  = (const float*)d_in[7];
  const float* Wm  = (const float*)d_in[8];
  const float* Wq  = (const float*)d_in[9];
  const float* vv  = (const float*)d_in[10];
  const float* Wa  = (const float*)d_in[11];
  const float* Wf  = (const float*)d_in[12];
  const float* bf  = (const float*)d_in[13];
  float* out = (float*)d_out;

  // ---- workspace carving ----
  char* w = (char*)d_ws; size_t off = 0;
  auto alloc = [&](size_t bytes)->char*{ char* p = w + off; off = (off + bytes + 255) & ~(size_t)255; return p; };
  u16* WfT   = (u16*)alloc((size_t)34004*512*2);
  u16* attn2 = (u16*)alloc((size_t)3776*512*2);
  size_t liveEnd = off;
  const size_t needB = (size_t)131<<20;
  bool fits = (ws_size >= liveEnd + needB);
  char* wb = fits ? (w + liveEnd) : (char*)d_out;
  size_t offb = 0;
  auto allocB = [&](size_t bytes)->char*{ char* p = wb + offb; offb = (offb + bytes + 255) & ~(size_t)255; return p; };

  u16* wzT   = (u16*)allocB((size_t)2048*3072*2);
  u16* buhT  = (u16*)allocB((size_t)2048*1024*2);
  u16* wq2   = (u16*)allocB((size_t)512*512*2);
  u16* waT   = (u16*)allocB((size_t)512*1536*2);
  u16* wmT   = (u16*)allocB((size_t)512*1024*2);
  u16* wxtpT = (u16*)allocB((size_t)2048*320*2);
  u16* wxaT  = (u16*)allocB((size_t)2048*1536*2);
  u16* waA   = (u16*)allocB((size_t)1536*1536*2);
  float* wzc = (float*)allocB((size_t)2048*1536*4);
  u16* embB  = (u16*)allocB((size_t)3776*320*2);
  u16* encB  = (u16*)allocB((size_t)2048*1024*2);
  float* Zemb  = (float*)allocB((size_t)3776*2048*4);
  float* keys  = (float*)allocB((size_t)2048*512*4);
  float* zparts= (float*)allocB((size_t)9*64*2048*4);
  float* cst   = (float*)allocB((size_t)64*512*4);
  float* bp    = (float*)allocB((size_t)2048*4);
  u16* A2c   = (u16*)allocB((size_t)3776*1536*2);
  u16* hhi   = (u16*)allocB((size_t)64*1536*2);
  u16* hlo   = (u16*)allocB((size_t)64*1536*2);
  unsigned* flags = (unsigned*)allocB((size_t)59*512*4);

  // ---- precompute: ONE mega-builder launch ----
  k_build<<<12588,256,0,stream>>>(bb, eh, ec, dec, enc, emb, Wx, Uh, Wm, Wq, Wa, Wf,
                                  bp, cst, flags,
                                  hhi, hlo, encB, wq2, wmT, waT,
                                  wxtpT, wxaT, buhT, waA, embB, WfT);

  // merged GEMMs: Zemb + keys + WzcT
  k_gemm3<<<736,256,0,stream>>>(embB, wxtpT, Zemb, bp, encB, wmT, keys, wxaT, waA, wzc);
  // W'z^T = split( WzcT + Uh(top) )^T   [2048][3072]
  k_wzcT<<<(2048*384+255)/256,256,0,stream>>>(wzc, Uh, wzT);

  // ---- recurrence: ONE fused launch per step ----
  for (int t=0; t<59; ++t){
    step_fused<<<320,512,0,stream>>>(t, wzT, buhT, hhi, hlo, zparts, Zemb,
                                     cst, wq2, keys, encB, vv, flags, A2c);
  }

  // ---- deferred attn2 + logits ----
  gemm_bf16<2><<<dim3(4,30),256,0,stream>>>(A2c, waT, 3776, 512, 1536, nullptr, attn2, nullptr, nullptr);
  gemm_bf16<3><<<dim3(266,30),256,0,stream>>>(attn2, WfT, 3776, 34004, 512, nullptr, nullptr, bf, out);
}